// Round 4
// baseline (99.632 us; speedup 1.0000x reference)
//
#include <hip/hip_runtime.h>
#include <math.h>

typedef _Float16 f16;
typedef __attribute__((ext_vector_type(8))) _Float16 f16x8;
typedef __attribute__((ext_vector_type(4))) _Float16 f16x4;
typedef __attribute__((ext_vector_type(4))) float f32x4;
typedef __attribute__((ext_vector_type(16))) float f32x16;

#define MFMA16(a, b, c) __builtin_amdgcn_mfma_f32_16x16x32_f16((a), (b), (c), 0, 0, 0)
#define MFMA32(a, b, c) __builtin_amdgcn_mfma_f32_32x32x16_f16((a), (b), (c), 0, 0, 0)

__device__ __forceinline__ void gld16(const f16* g, f16* l) {
  __builtin_amdgcn_global_load_lds(
      (const __attribute__((address_space(1))) unsigned int*)g,
      (__attribute__((address_space(3))) unsigned int*)l, 16, 0, 0);
}

__device__ __forceinline__ f16x8 pack8(const float* src) {
  float4 f0 = *(const float4*)src;
  float4 f1 = *(const float4*)(src + 4);
  f16x8 v;
  v[0] = (f16)f0.x; v[1] = (f16)f0.y; v[2] = (f16)f0.z; v[3] = (f16)f0.w;
  v[4] = (f16)f1.x; v[5] = (f16)f1.y; v[6] = (f16)f1.z; v[7] = (f16)f1.w;
  return v;
}

// ---------------- prep: ew = exp(wbias) as f16 [4096][4096] ----------------
__global__ __launch_bounds__(256) void prep_ew(const float* __restrict__ wb,
                                               f16* __restrict__ ew) {
  const size_t stride = (size_t)gridDim.x * 256;
  const size_t total = (size_t)4096 * 4096 / 4;
  for (size_t i = (size_t)blockIdx.x * 256 + threadIdx.x; i < total; i += stride) {
    float4 f = ((const float4*)wb)[i];
    f16x4 o;
    o.x = (f16)expf(f.x); o.y = (f16)expf(f.y);
    o.z = (f16)expf(f.z); o.w = (f16)expf(f.w);
    ((f16x4*)ew)[i] = o;
  }
}

// ---------------- prep: cast weights to f16 ----------------
__global__ __launch_bounds__(256) void prep_w(const float* __restrict__ wq,
                                              const float* __restrict__ wk,
                                              const float* __restrict__ wv,
                                              const float* __restrict__ wp,
                                              f16* __restrict__ wqkvb,
                                              f16* __restrict__ wpb) {
  int i = blockIdx.x * 256 + threadIdx.x;  // grid = 128 -> i in [0, 32768)
  wqkvb[i] = (f16)wk[i];
  wqkvb[32768 + i] = (f16)wv[i];
  wqkvb[65536 + i] = (f16)wq[i];
  wpb[i] = (f16)wp[i];
}

// ---------------- k1_qkv: sigQ[m][h], XT[b*128+h][t]=eK*V, XT[b*128+64+h][t]=eK --------
__global__ __launch_bounds__(256) void k1_qkv(const float* __restrict__ x,
                                              const f16* __restrict__ wqkvb,
                                              const float* __restrict__ bq,
                                              const float* __restrict__ bk,
                                              const float* __restrict__ bv,
                                              f16* __restrict__ sigQ,
                                              f16* __restrict__ XT) {
  __shared__ alignas(16) f16 sW[192 * 64];
  __shared__ alignas(16) f16 sX[64 * 64];
  const int tid = threadIdx.x;
  const int wave = tid >> 6, lane = tid & 63;
  const int m0 = blockIdx.x * 64;
  const int l15 = lane & 15;

  f32x4 accQ[4], accK[4], accV[4];
#pragma unroll
  for (int j = 0; j < 4; ++j) {
    accQ[j] = (f32x4){0.f, 0.f, 0.f, 0.f};
    accK[j] = (f32x4){0.f, 0.f, 0.f, 0.f};
    accV[j] = (f32x4){0.f, 0.f, 0.f, 0.f};
  }

  const int sc8 = tid & 7;
  const int wr8 = (tid >> 3) & 7;
  const int wcol = (sc8 ^ wr8) * 8;

  for (int ks = 0; ks < 512; ks += 64) {
#pragma unroll
    for (int q = 0; q < 6; ++q) {
      int r = q * 32 + (tid >> 3);
      gld16(wqkvb + (size_t)r * 512 + ks + wcol, &sW[r * 64 + sc8 * 8]);
    }
#pragma unroll
    for (int u = 0; u < 2; ++u) {
      int un = tid + u * 256;
      int r = un >> 3, c8 = un & 7;
      *(f16x8*)&sX[r * 64 + ((c8 ^ (r & 7)) * 8)] =
          pack8(x + (size_t)(m0 + r) * 512 + ks + c8 * 8);
    }
    __syncthreads();
#pragma unroll
    for (int kk = 0; kk < 2; ++kk) {
      const int c = kk * 4 + (lane >> 4);
      const int rK = wave * 16 + l15;
      const int rV = 64 + rK;
      f16x8 aK = *(const f16x8*)&sW[rK * 64 + ((c ^ (rK & 7)) * 8)];
      f16x8 aV = *(const f16x8*)&sW[rV * 64 + ((c ^ (rV & 7)) * 8)];
      f16x8 aQ = *(const f16x8*)&sX[rK * 64 + ((c ^ (rK & 7)) * 8)];
#pragma unroll
      for (int j = 0; j < 4; ++j) {
        const int rX = j * 16 + l15;
        const int rWq = 128 + j * 16 + l15;
        f16x8 bx = *(const f16x8*)&sX[rX * 64 + ((c ^ (rX & 7)) * 8)];
        f16x8 bw = *(const f16x8*)&sW[rWq * 64 + ((c ^ (rWq & 7)) * 8)];
        accK[j] = MFMA16(aK, bx, accK[j]);
        accV[j] = MFMA16(aV, bx, accV[j]);
        accQ[j] = MFMA16(aQ, bw, accQ[j]);
      }
    }
    __syncthreads();
  }
  const int b = m0 >> 12, t0 = m0 & 4095;
#pragma unroll
  for (int j = 0; j < 4; ++j) {
    const int h = j * 16 + l15;
    const float bqv = bq[h];
#pragma unroll
    for (int r = 0; r < 4; ++r) {
      const int m = m0 + wave * 16 + (lane >> 4) * 4 + r;
      const float v = accQ[j][r] + bqv;
      sigQ[(size_t)m * 64 + h] = (f16)(1.f / (1.f + expf(-v)));
    }
  }
#pragma unroll
  for (int r = 0; r < 4; ++r) {
    const int h = wave * 16 + (lane >> 4) * 4 + r;
    const float bkv = bk[h], bvv = bv[h];
    const size_t rowKV = (size_t)(b * 128 + h) * 4096;
    const size_t rowK = (size_t)(b * 128 + 64 + h) * 4096;
#pragma unroll
    for (int j = 0; j < 4; ++j) {
      const int t = t0 + j * 16 + l15;
      const float ek = expf(accK[j][r] + bkv);
      const float ev = accV[j][r] + bvv;
      XT[rowKV + t] = (f16)(ek * ev);
      XT[rowK + t] = (f16)ek;
    }
  }
}

// ---------------- k2_big: Yt = sigQ * (ew@num^T)/(ew@den^T), fused ----------------
// 512 thr, 8 waves, BM=BN=128 (one batch: 64 num + 64 den cols), BK=128.
// In-block K-split-4: wave pair kq=wave>>1 owns K-quarter; wave tile 128x64
// (acc[4][2] f32x16). Cols per wave: j*64 + ws*32 + (lane&31) so num/den pair
// in-register. Counted-vmcnt double-buffer, XOR-16 swizzle, XCD-aware bid map.
// 2-step LDS tree-merge of the 4 K-partials, then fused div/sigmoid epilogue.
__global__ __launch_bounds__(512, 2) void k2_big(const f16* __restrict__ A,
                                                 const f16* __restrict__ Bm,
                                                 const f16* __restrict__ sigQ,
                                                 f16* __restrict__ Yt) {
  __shared__ alignas(16) f16 smem[4][128 * 128];  // A buf 0/1, B buf 0/1 (128 KB)
  const int tid = threadIdx.x;
  const int wave = tid >> 6, lane = tid & 63;
  const int kq = wave >> 1;  // K-quarter 0..3
  const int ws = wave & 1;   // col-half within num (and den)
  const int bid = blockIdx.x;
  const int b = (bid >> 3) & 7;
  const int m0 = ((bid & 7) + 8 * (bid >> 6)) * 128;  // same-m blocks share XCD
  const f16* Bbase = Bm + (size_t)(b * 128) * 4096;

  const int srow = tid >> 4;   // 0..31
  const int sc16 = tid & 15;   // chunk 0..15
  const int gcol = (sc16 ^ (srow & 15)) * 8;  // pre-swizzled source col

  f32x16 acc[4][2];
#pragma unroll
  for (int i = 0; i < 4; ++i)
#pragma unroll
    for (int j = 0; j < 2; ++j)
#pragma unroll
      for (int r = 0; r < 16; ++r) acc[i][j][r] = 0.f;

#define K2_STAGE(buf, ks)                                                          \
  do {                                                                             \
    _Pragma("unroll") for (int q = 0; q < 4; ++q) {                                \
      int r = q * 32 + srow;                                                       \
      gld16(A + (size_t)(m0 + r) * 4096 + (ks) + gcol,                             \
            &smem[buf][r * 128 + sc16 * 8]);                                       \
      gld16(Bbase + (size_t)r * 4096 + (ks) + gcol,                                \
            &smem[2 + (buf)][r * 128 + sc16 * 8]);                                 \
    }                                                                              \
  } while (0)

  K2_STAGE(0, 0);
  K2_STAGE(1, 128);
  asm volatile("s_waitcnt vmcnt(8)" ::: "memory");  // tile 0's 8 loads landed
  __builtin_amdgcn_s_barrier();
  asm volatile("" ::: "memory");

  const int l31 = lane & 31, l15 = lane & 15, lhi = lane >> 5;
  const int c0 = kq * 4 + lhi;         // kk=0 chunk
  const int cx0 = (c0 ^ l15) * 8;
  const int cx1 = ((c0 + 2) ^ l15) * 8;  // kk=1 chunk
  const int nk = 4096 / 128;
  for (int t = 0; t < nk; ++t) {
    const int buf = t & 1;
    const f16* pA = smem[buf];
    const f16* pB = smem[2 + buf];
    f16x8 a0[4], a1[4], b0[2], b1[2];
#pragma unroll
    for (int i = 0; i < 4; ++i) a0[i] = *(const f16x8*)&pA[(i * 32 + l31) * 128 + cx0];
#pragma unroll
    for (int j = 0; j < 2; ++j)
      b0[j] = *(const f16x8*)&pB[(j * 64 + ws * 32 + l31) * 128 + cx0];
#pragma unroll
    for (int i = 0; i < 4; ++i) a1[i] = *(const f16x8*)&pA[(i * 32 + l31) * 128 + cx1];
#pragma unroll
    for (int j = 0; j < 2; ++j)
      b1[j] = *(const f16x8*)&pB[(j * 64 + ws * 32 + l31) * 128 + cx1];
    __builtin_amdgcn_s_setprio(1);
#pragma unroll
    for (int i = 0; i < 4; ++i)
#pragma unroll
      for (int j = 0; j < 2; ++j) acc[i][j] = MFMA32(a0[i], b0[j], acc[i][j]);
#pragma unroll
    for (int i = 0; i < 4; ++i)
#pragma unroll
      for (int j = 0; j < 2; ++j) acc[i][j] = MFMA32(a1[i], b1[j], acc[i][j]);
    __builtin_amdgcn_s_setprio(0);
    if (t + 1 < nk) {
      asm volatile("s_waitcnt lgkmcnt(0)" ::: "memory");
      __builtin_amdgcn_s_barrier();  // all waves done reading buf
      asm volatile("" ::: "memory");
      if (t + 2 < nk) {
        K2_STAGE(buf, (t + 2) * 128);
        asm volatile("s_waitcnt vmcnt(8)" ::: "memory");  // tile t+1 landed
      } else {
        asm volatile("s_waitcnt vmcnt(0)" ::: "memory");
      }
      __builtin_amdgcn_s_barrier();  // tile t+1 ready
      asm volatile("" ::: "memory");
    }
  }
#undef K2_STAGE

  // ---- tree-merge of 4 K-partials through LDS (128 KB scratch) ----
  __syncthreads();
  float* scr = (float*)smem;
  const int rit0 = 4 * lhi;
#define MRG_ADDR(reg, i, j, r) \
  ((reg) * 16384 + ((i) * 32 + ((r) & 3) + 8 * ((r) >> 2) + rit0) * 128 + (j) * 64 + ws * 32 + l31)
  if (kq & 1) {  // kq 1,3 write regions 0,1
#pragma unroll
    for (int i = 0; i < 4; ++i)
#pragma unroll
      for (int j = 0; j < 2; ++j)
#pragma unroll
        for (int r = 0; r < 16; ++r) scr[MRG_ADDR(kq >> 1, i, j, r)] = acc[i][j][r];
  }
  __syncthreads();
  if (!(kq & 1)) {  // kq 0,2 accumulate
#pragma unroll
    for (int i = 0; i < 4; ++i)
#pragma unroll
      for (int j = 0; j < 2; ++j)
#pragma unroll
        for (int r = 0; r < 16; ++r) acc[i][j][r] += scr[MRG_ADDR(kq >> 1, i, j, r)];
  }
  __syncthreads();
  if (kq == 2) {  // write merged upper half to region 0
#pragma unroll
    for (int i = 0; i < 4; ++i)
#pragma unroll
      for (int j = 0; j < 2; ++j)
#pragma unroll
        for (int r = 0; r < 16; ++r) scr[MRG_ADDR(0, i, j, r)] = acc[i][j][r];
  }
  __syncthreads();
  if (kq == 0) {  // final sum + fused epilogue
#pragma unroll
    for (int i = 0; i < 4; ++i)
#pragma unroll
      for (int j = 0; j < 2; ++j)
#pragma unroll
        for (int r = 0; r < 16; ++r) acc[i][j][r] += scr[MRG_ADDR(0, i, j, r)];
    const int h = ws * 32 + l31;
#pragma unroll
    for (int i = 0; i < 4; ++i)
#pragma unroll
      for (int r = 0; r < 16; ++r) {
        const int trow = m0 + i * 32 + (r & 3) + 8 * (r >> 2) + rit0;
        const size_t mrow = (size_t)b * 4096 + trow;
        const float sq = (float)sigQ[mrow * 64 + h];
        Yt[mrow * 64 + h] = (f16)(sq * acc[i][0][r] / acc[i][1][r]);
      }
  }
#undef MRG_ADDR
}

// ---------------- k4_out: out[m][d] = Yt @ wp^T + bp (f32 out) ----------------
__global__ __launch_bounds__(256) void k4_out(const f16* __restrict__ Yt,
                                              const f16* __restrict__ wpb,
                                              const float* __restrict__ bp,
                                              float* __restrict__ out) {
  __shared__ alignas(16) f16 sA[128 * 64];
  __shared__ alignas(16) f16 sB[128 * 64];
  const int tid = threadIdx.x;
  const int wave = tid >> 6, lane = tid & 63;
  const int m0 = blockIdx.x * 128;  // 256
  const int n0 = blockIdx.y * 128;  // 4
  const int wm = (wave >> 1) * 64;
  const int wn = (wave & 1) * 64;
  const int l15 = lane & 15;
  const int sc8 = tid & 7;
  const int scol = (sc8 ^ ((tid >> 3) & 7)) * 8;

#pragma unroll
  for (int q = 0; q < 4; ++q) {
    int r = q * 32 + (tid >> 3);
    gld16(Yt + (size_t)(m0 + r) * 64 + scol, &sA[r * 64 + sc8 * 8]);
    gld16(wpb + (size_t)(n0 + r) * 64 + scol, &sB[r * 64 + sc8 * 8]);
  }
  __syncthreads();

  f32x4 acc[4][4];
#pragma unroll
  for (int i = 0; i < 4; ++i)
#pragma unroll
    for (int j = 0; j < 4; ++j) acc[i][j] = (f32x4){0.f, 0.f, 0.f, 0.f};

#pragma unroll
  for (int kk = 0; kk < 2; ++kk) {
    const int c = kk * 4 + (lane >> 4);
    f16x8 af[4], bfr[4];
#pragma unroll
    for (int i = 0; i < 4; ++i) {
      const int r = wm + i * 16 + l15;
      af[i] = *(const f16x8*)&sA[r * 64 + ((c ^ (r & 7)) * 8)];
    }
#pragma unroll
    for (int j = 0; j < 4; ++j) {
      const int r = wn + j * 16 + l15;
      bfr[j] = *(const f16x8*)&sB[r * 64 + ((c ^ (r & 7)) * 8)];
    }
#pragma unroll
    for (int i = 0; i < 4; ++i)
#pragma unroll
      for (int j = 0; j < 4; ++j) acc[i][j] = MFMA16(af[i], bfr[j], acc[i][j]);
  }

#pragma unroll
  for (int i = 0; i < 4; ++i) {
    const int row = m0 + wm + i * 16 + (lane >> 4) * 4;
#pragma unroll
    for (int j = 0; j < 4; ++j) {
      const int col = n0 + wn + j * 16 + l15;
      const float bpv = bp[col];
#pragma unroll
      for (int r = 0; r < 4; ++r)
        out[(size_t)(row + r) * 512 + col] = acc[i][j][r] + bpv;
    }
  }
}

extern "C" void kernel_launch(void* const* d_in, const int* in_sizes, int n_in,
                              void* d_out, int out_size, void* d_ws, size_t ws_size,
                              hipStream_t stream) {
  const float* x = (const float*)d_in[0];
  const float* wq = (const float*)d_in[1];
  const float* bq = (const float*)d_in[2];
  const float* wk = (const float*)d_in[3];
  const float* bk = (const float*)d_in[4];
  const float* wv = (const float*)d_in[5];
  const float* bv = (const float*)d_in[6];
  const float* wp = (const float*)d_in[7];
  const float* bp = (const float*)d_in[8];
  const float* wbias = (const float*)d_in[9];
  float* out = (float*)d_out;

  char* ws = (char*)d_ws;
  f16* ew = (f16*)(ws);                  // 33,554,432 B
  f16* XT = (f16*)(ws + 33554432);       //  8,388,608 B
  f16* sigQ = (f16*)(ws + 41943040);     //  4,194,304 B
  f16* Yt = (f16*)(ws + 46137344);       //  4,194,304 B
  f16* wqkvb = (f16*)(ws + 50331648);    //    196,608 B
  f16* wpb = (f16*)(ws + 50528256);      //     65,536 B (end 50,593,792)

  prep_ew<<<4096, 256, 0, stream>>>(wbias, ew);
  prep_w<<<128, 256, 0, stream>>>(wq, wk, wv, wp, wqkvb, wpb);
  k1_qkv<<<512, 256, 0, stream>>>(x, wqkvb, bq, bk, bv, sigQ, XT);
  k2_big<<<256, 512, 0, stream>>>(ew, XT, sigQ, Yt);
  k4_out<<<dim3(256, 4), 256, 0, stream>>>(Yt, wpb, bp, out);
}

// Round 5
// 99.328 us; speedup vs baseline: 1.0031x; 1.0031x over previous
//
#include <hip/hip_runtime.h>
#include <math.h>

typedef _Float16 f16;
typedef __attribute__((ext_vector_type(8))) _Float16 f16x8;
typedef __attribute__((ext_vector_type(4))) _Float16 f16x4;
typedef __attribute__((ext_vector_type(4))) float f32x4;
typedef __attribute__((ext_vector_type(16))) float f32x16;

#define MFMA16(a, b, c) __builtin_amdgcn_mfma_f32_16x16x32_f16((a), (b), (c), 0, 0, 0)
#define MFMA32(a, b, c) __builtin_amdgcn_mfma_f32_32x32x16_f16((a), (b), (c), 0, 0, 0)

__device__ __forceinline__ void gld16(const f16* g, f16* l) {
  __builtin_amdgcn_global_load_lds(
      (const __attribute__((address_space(1))) unsigned int*)g,
      (__attribute__((address_space(3))) unsigned int*)l, 16, 0, 0);
}

__device__ __forceinline__ f16x8 pack8(const float* src) {
  float4 f0 = *(const float4*)src;
  float4 f1 = *(const float4*)(src + 4);
  f16x8 v;
  v[0] = (f16)f0.x; v[1] = (f16)f0.y; v[2] = (f16)f0.z; v[3] = (f16)f0.w;
  v[4] = (f16)f1.x; v[5] = (f16)f1.y; v[6] = (f16)f1.z; v[7] = (f16)f1.w;
  return v;
}

// ---------------- prep: ew = exp(wbias) as f16 [4096][4096] ----------------
__global__ __launch_bounds__(256) void prep_ew(const float* __restrict__ wb,
                                               f16* __restrict__ ew) {
  const size_t stride = (size_t)gridDim.x * 256;
  const size_t total = (size_t)4096 * 4096 / 4;
  for (size_t i = (size_t)blockIdx.x * 256 + threadIdx.x; i < total; i += stride) {
    float4 f = ((const float4*)wb)[i];
    f16x4 o;
    o.x = (f16)expf(f.x); o.y = (f16)expf(f.y);
    o.z = (f16)expf(f.z); o.w = (f16)expf(f.w);
    ((f16x4*)ew)[i] = o;
  }
}

// ---------------- prep: cast weights to f16 ----------------
__global__ __launch_bounds__(256) void prep_w(const float* __restrict__ wq,
                                              const float* __restrict__ wk,
                                              const float* __restrict__ wv,
                                              const float* __restrict__ wp,
                                              f16* __restrict__ wqkvb,
                                              f16* __restrict__ wpb) {
  int i = blockIdx.x * 256 + threadIdx.x;  // grid = 128 -> i in [0, 32768)
  wqkvb[i] = (f16)wk[i];
  wqkvb[32768 + i] = (f16)wv[i];
  wqkvb[65536 + i] = (f16)wq[i];
  wpb[i] = (f16)wp[i];
}

// ---------------- k1_qkv: sigQ[m][h], XT[b*128+h][t]=eK*V, XT[b*128+64+h][t]=eK --------
__global__ __launch_bounds__(256) void k1_qkv(const float* __restrict__ x,
                                              const f16* __restrict__ wqkvb,
                                              const float* __restrict__ bq,
                                              const float* __restrict__ bk,
                                              const float* __restrict__ bv,
                                              f16* __restrict__ sigQ,
                                              f16* __restrict__ XT) {
  __shared__ alignas(16) f16 sW[192 * 64];
  __shared__ alignas(16) f16 sX[64 * 64];
  const int tid = threadIdx.x;
  const int wave = tid >> 6, lane = tid & 63;
  const int m0 = blockIdx.x * 64;
  const int l15 = lane & 15;

  f32x4 accQ[4], accK[4], accV[4];
#pragma unroll
  for (int j = 0; j < 4; ++j) {
    accQ[j] = (f32x4){0.f, 0.f, 0.f, 0.f};
    accK[j] = (f32x4){0.f, 0.f, 0.f, 0.f};
    accV[j] = (f32x4){0.f, 0.f, 0.f, 0.f};
  }

  const int sc8 = tid & 7;
  const int wr8 = (tid >> 3) & 7;
  const int wcol = (sc8 ^ wr8) * 8;

  for (int ks = 0; ks < 512; ks += 64) {
#pragma unroll
    for (int q = 0; q < 6; ++q) {
      int r = q * 32 + (tid >> 3);
      gld16(wqkvb + (size_t)r * 512 + ks + wcol, &sW[r * 64 + sc8 * 8]);
    }
#pragma unroll
    for (int u = 0; u < 2; ++u) {
      int un = tid + u * 256;
      int r = un >> 3, c8 = un & 7;
      *(f16x8*)&sX[r * 64 + ((c8 ^ (r & 7)) * 8)] =
          pack8(x + (size_t)(m0 + r) * 512 + ks + c8 * 8);
    }
    __syncthreads();
#pragma unroll
    for (int kk = 0; kk < 2; ++kk) {
      const int c = kk * 4 + (lane >> 4);
      const int rK = wave * 16 + l15;
      const int rV = 64 + rK;
      f16x8 aK = *(const f16x8*)&sW[rK * 64 + ((c ^ (rK & 7)) * 8)];
      f16x8 aV = *(const f16x8*)&sW[rV * 64 + ((c ^ (rV & 7)) * 8)];
      f16x8 aQ = *(const f16x8*)&sX[rK * 64 + ((c ^ (rK & 7)) * 8)];
#pragma unroll
      for (int j = 0; j < 4; ++j) {
        const int rX = j * 16 + l15;
        const int rWq = 128 + j * 16 + l15;
        f16x8 bx = *(const f16x8*)&sX[rX * 64 + ((c ^ (rX & 7)) * 8)];
        f16x8 bw = *(const f16x8*)&sW[rWq * 64 + ((c ^ (rWq & 7)) * 8)];
        accK[j] = MFMA16(aK, bx, accK[j]);
        accV[j] = MFMA16(aV, bx, accV[j]);
        accQ[j] = MFMA16(aQ, bw, accQ[j]);
      }
    }
    __syncthreads();
  }
  const int b = m0 >> 12, t0 = m0 & 4095;
#pragma unroll
  for (int j = 0; j < 4; ++j) {
    const int h = j * 16 + l15;
    const float bqv = bq[h];
#pragma unroll
    for (int r = 0; r < 4; ++r) {
      const int m = m0 + wave * 16 + (lane >> 4) * 4 + r;
      const float v = accQ[j][r] + bqv;
      sigQ[(size_t)m * 64 + h] = (f16)(1.f / (1.f + expf(-v)));
    }
  }
#pragma unroll
  for (int r = 0; r < 4; ++r) {
    const int h = wave * 16 + (lane >> 4) * 4 + r;
    const float bkv = bk[h], bvv = bv[h];
    const size_t rowKV = (size_t)(b * 128 + h) * 4096;
    const size_t rowK = (size_t)(b * 128 + 64 + h) * 4096;
#pragma unroll
    for (int j = 0; j < 4; ++j) {
      const int t = t0 + j * 16 + l15;
      const float ek = expf(accK[j][r] + bkv);
      const float ev = accV[j][r] + bvv;
      XT[rowKV + t] = (f16)(ek * ev);
      XT[rowK + t] = (f16)ek;
    }
  }
}

// ---------------- k2_big: Yt = sigQ * (ew@num^T)/(ew@den^T), fused ----------------
// 512 thr, 8 waves, BM=BN=128, BK=64, TRIPLE-buffered LDS (3 x 32KB).
// One barrier + one lgkmcnt(0) + one counted vmcnt(4) per K-tile: 2 tiles of
// global_load_lds always in flight, DMA streams during MFMA (T3/T4 minimum-
// phase pipeline). K-split-4 (kq=wave>>1), wave tile 128x64, in-register
// num/den pairing; XOR-8 swizzle both-sides; XCD-aware bid map. 3-round LDS
// tree-merge of K-partials, then fused sigmoid*num/den epilogue.
__global__ __launch_bounds__(512) void k2_big(const f16* __restrict__ A,
                                              const f16* __restrict__ Bm,
                                              const f16* __restrict__ sigQ,
                                              f16* __restrict__ Yt) {
  __shared__ alignas(16) f16 smem[3 * 16384];  // 96 KB: per buf A[128][64]+B[128][64]
  const int tid = threadIdx.x;
  const int wave = tid >> 6, lane = tid & 63;
  const int kq = wave >> 1;  // K-quarter 0..3 (16 k of each BK=64 tile)
  const int ws = wave & 1;   // 32-col half within num (and den)
  const int bid = blockIdx.x;
  const int b = (bid >> 3) & 7;
  const int m0 = ((bid & 7) + 8 * (bid >> 6)) * 128;  // same-m blocks share XCD
  const f16* Bb = Bm + (size_t)(b * 128) * 4096;

  const int srow8 = tid >> 3;  // 0..63
  const int sc8 = tid & 7;
  const int gsw = (sc8 ^ (srow8 & 7)) * 8;   // pre-swizzled source col
  const int dlin = srow8 * 64 + sc8 * 8;     // linear LDS dest (elems)

  f32x16 acc[4][2];
#pragma unroll
  for (int i = 0; i < 4; ++i)
#pragma unroll
    for (int j = 0; j < 2; ++j)
#pragma unroll
      for (int r = 0; r < 16; ++r) acc[i][j][r] = 0.f;

#define K2_STAGE(bb, ks)                                                         \
  do {                                                                           \
    gld16(A + (size_t)(m0 + srow8) * 4096 + (ks) + gsw, &smem[(bb) + dlin]);     \
    gld16(A + (size_t)(m0 + 64 + srow8) * 4096 + (ks) + gsw,                     \
          &smem[(bb) + 4096 + dlin]);                                            \
    gld16(Bb + (size_t)srow8 * 4096 + (ks) + gsw, &smem[(bb) + 8192 + dlin]);    \
    gld16(Bb + (size_t)(64 + srow8) * 4096 + (ks) + gsw,                         \
          &smem[(bb) + 12288 + dlin]);                                           \
  } while (0)

  // prologue: tiles 0,1 in flight; wait tile 0
  K2_STAGE(0, 0);
  K2_STAGE(16384, 64);
  asm volatile("s_waitcnt vmcnt(4)" ::: "memory");
  __builtin_amdgcn_sched_barrier(0);
  __builtin_amdgcn_s_barrier();

  const int l31 = lane & 31, lhi = lane >> 5;
  const int cx = ((kq * 2 + lhi) ^ (lane & 7)) * 8;  // swizzled k-chunk
  const int nk = 64;
  int bb = 0;  // (t%3) * 16384
  for (int t = 0; t < nk; ++t) {
    // stage tile t+2 into buffer (t+2)%3 (its readers drained at barrier t-1)
    int bb2 = bb + 32768;
    if (bb2 >= 49152) bb2 -= 49152;
    if (t < nk - 2) K2_STAGE(bb2, (t + 2) * 64);
    // register fragments for tile t
    const f16* pA = &smem[bb];
    const f16* pB = &smem[bb + 8192];
    f16x8 af[4], bf2[2];
#pragma unroll
    for (int i = 0; i < 4; ++i) af[i] = *(const f16x8*)&pA[(i * 32 + l31) * 64 + cx];
#pragma unroll
    for (int j = 0; j < 2; ++j)
      bf2[j] = *(const f16x8*)&pB[(j * 64 + ws * 32 + l31) * 64 + cx];
    asm volatile("s_waitcnt lgkmcnt(0)" ::: "memory");
    __builtin_amdgcn_sched_barrier(0);
    __builtin_amdgcn_s_setprio(1);
#pragma unroll
    for (int i = 0; i < 4; ++i)
#pragma unroll
      for (int j = 0; j < 2; ++j) acc[i][j] = MFMA32(af[i], bf2[j], acc[i][j]);
    __builtin_amdgcn_s_setprio(0);
    // tile t+1 must be resident before next iteration's reads (all waves)
    if (t < nk - 2) {
      asm volatile("s_waitcnt vmcnt(4)" ::: "memory");
    } else {
      asm volatile("s_waitcnt vmcnt(0)" ::: "memory");
    }
    __builtin_amdgcn_sched_barrier(0);
    __builtin_amdgcn_s_barrier();
    bb += 16384;
    if (bb == 49152) bb = 0;
  }
#undef K2_STAGE

  // ---- 3-round tree-merge of the 4 K-partials (64KB f32 region in smem) ----
  __syncthreads();
  float* scr = (float*)smem;
  const int rit0 = 4 * lhi;
#define MRG(i, j, r) \
  (((i) * 32 + ((r) & 3) + 8 * ((r) >> 2) + rit0) * 128 + (j) * 64 + ws * 32 + l31)
  if (kq == 1) {
#pragma unroll
    for (int i = 0; i < 4; ++i)
#pragma unroll
      for (int j = 0; j < 2; ++j)
#pragma unroll
        for (int r = 0; r < 16; ++r) scr[MRG(i, j, r)] = acc[i][j][r];
  }
  __syncthreads();
  if (kq == 0) {
#pragma unroll
    for (int i = 0; i < 4; ++i)
#pragma unroll
      for (int j = 0; j < 2; ++j)
#pragma unroll
        for (int r = 0; r < 16; ++r) acc[i][j][r] += scr[MRG(i, j, r)];
  }
  __syncthreads();
  if (kq == 3) {
#pragma unroll
    for (int i = 0; i < 4; ++i)
#pragma unroll
      for (int j = 0; j < 2; ++j)
#pragma unroll
        for (int r = 0; r < 16; ++r) scr[MRG(i, j, r)] = acc[i][j][r];
  }
  __syncthreads();
  if (kq == 2) {
#pragma unroll
    for (int i = 0; i < 4; ++i)
#pragma unroll
      for (int j = 0; j < 2; ++j)
#pragma unroll
        for (int r = 0; r < 16; ++r) acc[i][j][r] += scr[MRG(i, j, r)];
  }
  __syncthreads();
  if (kq == 2) {
#pragma unroll
    for (int i = 0; i < 4; ++i)
#pragma unroll
      for (int j = 0; j < 2; ++j)
#pragma unroll
        for (int r = 0; r < 16; ++r) scr[MRG(i, j, r)] = acc[i][j][r];
  }
  __syncthreads();
  if (kq == 0) {
#pragma unroll
    for (int i = 0; i < 4; ++i)
#pragma unroll
      for (int j = 0; j < 2; ++j)
#pragma unroll
        for (int r = 0; r < 16; ++r) acc[i][j][r] += scr[MRG(i, j, r)];
    // fused epilogue: Yt = sigQ * num / den
    const int h = ws * 32 + l31;
#pragma unroll
    for (int i = 0; i < 4; ++i)
#pragma unroll
      for (int r = 0; r < 16; ++r) {
        const int trow = m0 + i * 32 + (r & 3) + 8 * (r >> 2) + rit0;
        const size_t mrow = (size_t)b * 4096 + trow;
        const float sq = (float)sigQ[mrow * 64 + h];
        Yt[mrow * 64 + h] = (f16)(sq * acc[i][0][r] / acc[i][1][r]);
      }
  }
#undef MRG
}

// ---------------- k4_out: out[m][d] = Yt @ wp^T + bp (f32 out) ----------------
__global__ __launch_bounds__(256) void k4_out(const f16* __restrict__ Yt,
                                              const f16* __restrict__ wpb,
                                              const float* __restrict__ bp,
                                              float* __restrict__ out) {
  __shared__ alignas(16) f16 sA[128 * 64];
  __shared__ alignas(16) f16 sB[128 * 64];
  const int tid = threadIdx.x;
  const int wave = tid >> 6, lane = tid & 63;
  const int m0 = blockIdx.x * 128;  // 256
  const int n0 = blockIdx.y * 128;  // 4
  const int wm = (wave >> 1) * 64;
  const int wn = (wave & 1) * 64;
  const int l15 = lane & 15;
  const int sc8 = tid & 7;
  const int scol = (sc8 ^ ((tid >> 3) & 7)) * 8;

#pragma unroll
  for (int q = 0; q < 4; ++q) {
    int r = q * 32 + (tid >> 3);
    gld16(Yt + (size_t)(m0 + r) * 64 + scol, &sA[r * 64 + sc8 * 8]);
    gld16(wpb + (size_t)(n0 + r) * 64 + scol, &sB[r * 64 + sc8 * 8]);
  }
  __syncthreads();

  f32x4 acc[4][4];
#pragma unroll
  for (int i = 0; i < 4; ++i)
#pragma unroll
    for (int j = 0; j < 4; ++j) acc[i][j] = (f32x4){0.f, 0.f, 0.f, 0.f};

#pragma unroll
  for (int kk = 0; kk < 2; ++kk) {
    const int c = kk * 4 + (lane >> 4);
    f16x8 af[4], bfr[4];
#pragma unroll
    for (int i = 0; i < 4; ++i) {
      const int r = wm + i * 16 + l15;
      af[i] = *(const f16x8*)&sA[r * 64 + ((c ^ (r & 7)) * 8)];
    }
#pragma unroll
    for (int j = 0; j < 4; ++j) {
      const int r = wn + j * 16 + l15;
      bfr[j] = *(const f16x8*)&sB[r * 64 + ((c ^ (r & 7)) * 8)];
    }
#pragma unroll
    for (int i = 0; i < 4; ++i)
#pragma unroll
      for (int j = 0; j < 4; ++j) acc[i][j] = MFMA16(af[i], bfr[j], acc[i][j]);
  }

#pragma unroll
  for (int i = 0; i < 4; ++i) {
    const int row = m0 + wm + i * 16 + (lane >> 4) * 4;
#pragma unroll
    for (int j = 0; j < 4; ++j) {
      const int col = n0 + wn + j * 16 + l15;
      const float bpv = bp[col];
#pragma unroll
      for (int r = 0; r < 4; ++r)
        out[(size_t)(row + r) * 512 + col] = acc[i][j][r] + bpv;
    }
  }
}

extern "C" void kernel_launch(void* const* d_in, const int* in_sizes, int n_in,
                              void* d_out, int out_size, void* d_ws, size_t ws_size,
                              hipStream_t stream) {
  const float* x = (const float*)d_in[0];
  const float* wq = (const float*)d_in[1];
  const float* bq = (const float*)d_in[2];
  const float* wk = (const float*)d_in[3];
  const float* bk = (const float*)d_in[4];
  const float* wv = (const float*)d_in[5];
  const float* bv = (const float*)d_in[6];
  const float* wp = (const float*)d_in[7];
  const float* bp = (const float*)d_in[8];
  const float* wbias = (const float*)d_in[9];
  float* out = (float*)d_out;

  char* ws = (char*)d_ws;
  f16* ew = (f16*)(ws);                  // 33,554,432 B
  f16* XT = (f16*)(ws + 33554432);       //  8,388,608 B
  f16* sigQ = (f16*)(ws + 41943040);     //  4,194,304 B
  f16* Yt = (f16*)(ws + 46137344);       //  4,194,304 B
  f16* wqkvb = (f16*)(ws + 50331648);    //    196,608 B
  f16* wpb = (f16*)(ws + 50528256);      //     65,536 B (end 50,593,792)

  prep_ew<<<4096, 256, 0, stream>>>(wbias, ew);
  prep_w<<<128, 256, 0, stream>>>(wq, wk, wv, wp, wqkvb, wpb);
  k1_qkv<<<512, 256, 0, stream>>>(x, wqkvb, bq, bk, bv, sigQ, XT);
  k2_big<<<256, 512, 0, stream>>>(ew, XT, sigQ, Yt);
  k4_out<<<dim3(256, 4), 256, 0, stream>>>(Yt, wpb, bp, out);
}